// Round 9
// baseline (158.630 us; speedup 1.0000x reference)
//
#include <hip/hip_runtime.h>
#include <math.h>

// ---------------------------------------------------------------------------
// UniHeadSimple fused loss.  Round 9: global_load_lds DMA-path probe.
//   - each wave stages its own 2 rows into LDS via 16B global_load_lds
//     (8 instrs, 8 KB in flight), processes them after counted vmcnt waits
//   - no block barriers in the streaming loop (per-wave self-stage/consume)
//   - bps=64 chunks/sample (8 rows per block), 32 KB LDS, ~5 blocks/CU
// Inputs (setup_inputs order):
//   d_in[0] pred_mask   (B,1,H,W) f32
//   d_in[1] pred_bbox   (B,4)     f32
//   d_in[2] gt_bbox_rand(B,4)     f32
//   d_in[3] target_mask (B,H,W)   i32
//   d_in[4] img_h scalar i32   d_in[5] img_w scalar i32
// Output: single f32 scalar loss.
// ---------------------------------------------------------------------------

#define TPB 256         // threads per block (4 waves)

typedef float fx4 __attribute__((ext_vector_type(4)));
typedef int   ix4 __attribute__((ext_vector_type(4)));

// ---- per-sample box loss (L1 + (1 - GIoU)), inputs in xywh -----------------
__device__ inline float box_loss_xywh(const float pb[4], const float tb[4]) {
    float l1 = fabsf(pb[0] - tb[0]) + fabsf(pb[1] - tb[1]) +
               fabsf(pb[2] - tb[2]) + fabsf(pb[3] - tb[3]);
    float ax1 = pb[0] - 0.5f * pb[2], ay1 = pb[1] - 0.5f * pb[3];
    float ax2 = pb[0] + 0.5f * pb[2], ay2 = pb[1] + 0.5f * pb[3];
    float bx1 = tb[0] - 0.5f * tb[2], by1 = tb[1] - 0.5f * tb[3];
    float bx2 = tb[0] + 0.5f * tb[2], by2 = tb[1] + 0.5f * tb[3];

    float ix1 = fmaxf(ax1, bx1), iy1 = fmaxf(ay1, by1);
    float ix2 = fminf(ax2, bx2), iy2 = fminf(ay2, by2);
    float inter  = fmaxf(ix2 - ix1, 0.f) * fmaxf(iy2 - iy1, 0.f);
    float area_a = fmaxf(ax2 - ax1, 0.f) * fmaxf(ay2 - ay1, 0.f);
    float area_b = fmaxf(bx2 - bx1, 0.f) * fmaxf(by2 - by1, 0.f);
    float uni = area_a + area_b - inter;
    float iou = inter / fmaxf(uni, 1e-6f);
    float cx1 = fminf(ax1, bx1), cy1 = fminf(ay1, by1);
    float cx2 = fmaxf(ax2, bx2), cy2 = fmaxf(ay2, by2);
    float c = fmaxf(cx2 - cx1, 0.f) * fmaxf(cy2 - cy1, 0.f);
    float giou = iou - (c - uni) / fmaxf(c, 1e-6f);
    return l1 + (1.0f - giou);
}

__device__ __forceinline__ void gload16(const void* g, void* l) {
    __builtin_amdgcn_global_load_lds(
        (const __attribute__((address_space(1))) unsigned int*)g,
        (__attribute__((address_space(3))) unsigned int*)l, 16, 0, 0);
}

// ---------------------------------------------------------------------------
// Kernel 1: per-(sample,chunk) partial reductions over the mask.
// Chunk = 8 consecutive rows.  Wave w stages rows {2w, 2w+1} into LDS via
// global_load_lds, then processes them (lane l owns px [8l..8l+7] of a row).
// ws layout: float wf[3][N], int wi[7][N], N = B*nchunk.
//   wf: 0=sum(p*t)  1=sum(p)  2=sum(bce)
//   wi: 0=sum(t)    1=area    2=inter   3=xmin 4=ymin 5=xmax 6=ymax
// ---------------------------------------------------------------------------
__global__ __launch_bounds__(TPB)
void uh_reduce(const float* __restrict__ pred_mask,
               const int*   __restrict__ target_mask,
               const float* __restrict__ pred_bbox,
               const int*   __restrict__ pH, const int* __restrict__ pW,
               float* __restrict__ wf, int* __restrict__ wi,
               int HW, int N)
{
    const int b      = blockIdx.y;
    const int chunk  = blockIdx.x;
    const int nchunk = gridDim.x;
    const int W = *pW;
    const int H = *pH;

    // per-sample pred box in clipped pixel coords (uniform scalar loads)
    float c0 = pred_bbox[b * 4 + 0], c1 = pred_bbox[b * 4 + 1];
    float c2 = pred_bbox[b * 4 + 2], c3 = pred_bbox[b * 4 + 3];
    const int bx1 = min(max((int)((c0 - 0.5f * c2) * (float)W), 0), W);
    const int by1 = min(max((int)((c1 - 0.5f * c3) * (float)H), 0), H);
    const int bx2 = min(max((int)((c0 + 0.5f * c2) * (float)W), 0), W);
    const int by2 = min(max((int)((c1 + 0.5f * c3) * (float)H), 0), H);

    const int rows  = H / nchunk;        // 8
    const int rpw   = rows / 4;          // rows per wave (2)
    const int wv    = threadIdx.x >> 6;  // wave id
    const int l     = threadIdx.x & 63;  // lane
    const int ppl   = W >> 6;            // px per lane (8 for W=512)
    const int cx    = l * ppl;
    const int ybase = chunk * rows;
    const int kpr   = W >> 8;            // 16B-gloads per row per array (2)

    // 8-bit in_x mask for this lane's columns (loop-invariant)
    unsigned inxmask = 0;
    #pragma unroll 8
    for (int j = 0; j < 8; ++j)
        inxmask |= (unsigned)((cx + j >= bx1) & (cx + j < bx2)) << j;

    __shared__ float sp[8 * 512];        // 16 KB  pred rows
    __shared__ int   st[8 * 512];        // 16 KB  tgt rows

    // ---- stage this wave's rows: per row, 2x pred + 2x tgt gload_lds ----
    const long srow = (long)b * HW + (long)ybase * W;
    for (int r = 0; r < rpw; ++r) {
        const int rl = wv * rpw + r;
        const float* gp = pred_mask   + srow + (long)rl * W;
        const int*   gt = target_mask + srow + (long)rl * W;
        for (int k = 0; k < kpr; ++k)
            gload16(gp + k * 256 + l * 4, &sp[rl * 512 + k * 256]);
        for (int k = 0; k < kpr; ++k)
            gload16(gt + k * 256 + l * 4, &st[rl * 512 + k * 256]);
    }

    float s_pt = 0.f, s_p = 0.f, slg2 = 0.f, s_relu = 0.f;
    int c_t = 0, c_area = 0, c_inter = 0;
    unsigned rmask = 0, colmask = 0;

    #define PROC_ROW(RL)                                                      \
    {                                                                         \
        const int rl_ = (RL);                                                 \
        fx4 xa = *(const fx4*)&sp[rl_ * 512 + cx];                            \
        fx4 xb = *(const fx4*)&sp[rl_ * 512 + cx + 4];                        \
        ix4 ta = *(const ix4*)&st[rl_ * 512 + cx];                            \
        ix4 tb = *(const ix4*)&st[rl_ * 512 + cx + 4];                        \
        const float xs[8] = {xa[0], xa[1], xa[2], xa[3],                      \
                             xb[0], xb[1], xb[2], xb[3]};                     \
        const int   ts[8] = {ta[0], ta[1], ta[2], ta[3],                      \
                             tb[0], tb[1], tb[2], tb[3]};                     \
        unsigned m8 = 0;                                                      \
        _Pragma("unroll")                                                     \
        for (int j = 0; j < 8; ++j) {                                         \
            float xl = xs[j];                                                 \
            bool  t  = ts[j] != 0;                                            \
            float e  = __expf(-fabsf(xl));                                    \
            float r  = __builtin_amdgcn_rcpf(1.f + e);                        \
            slg2    += __log2f(r);                                            \
            float p  = (xl >= 0.f) ? r : 1.f - r;                             \
            s_p     += p;                                                     \
            s_pt    += t ? p : 0.f;                                           \
            s_relu  += fmaxf(t ? -xl : xl, 0.f);                              \
            c_t     += ts[j];                                                 \
            m8      |= (unsigned)(xl > 0.f) << j;                             \
        }                                                                     \
        c_area  += __popc(m8);                                                \
        const int y_ = ybase + rl_;                                           \
        c_inter += ((y_ >= by1) & (y_ < by2)) ? __popc(m8 & inxmask) : 0;     \
        colmask |= m8;                                                        \
        rmask   |= (m8 ? 1u : 0u) << rl_;                                     \
    }

    if (rpw == 2 && kpr == 2) {
        // counted waits: 8 gloads issued; first row needs the first 4.
        asm volatile("s_waitcnt vmcnt(4)" ::: "memory");
        __builtin_amdgcn_sched_barrier(0);
        PROC_ROW(wv * 2 + 0)
        asm volatile("s_waitcnt vmcnt(0)" ::: "memory");
        __builtin_amdgcn_sched_barrier(0);
        PROC_ROW(wv * 2 + 1)
    } else {
        asm volatile("s_waitcnt vmcnt(0)" ::: "memory");
        __builtin_amdgcn_sched_barrier(0);
        for (int r = 0; r < rpw; ++r)
            PROC_ROW(wv * rpw + r)
    }
    #undef PROC_ROW

    // bce total: sum relu(+-x) + sum log1p(e) ; log1p(e) = -ln2 * log2(r)
    float s_bce = fmaf(-0.69314718055994531f, slg2, s_relu);

    // bitmasks -> bbox candidates
    int xmn = W, xmx = -1, ymn = H, ymx = -1;
    if (colmask) {
        xmn = cx + (__ffs(colmask) - 1);
        xmx = cx + (31 - __clz(colmask));
    }
    if (rmask) {
        ymn = ybase + (__ffs(rmask) - 1);
        ymx = ybase + (31 - __clz(rmask));
    }

    // --- wave reduction (64 lanes) ---
    #pragma unroll
    for (int o = 32; o; o >>= 1) {
        s_pt  += __shfl_down(s_pt,  o, 64);
        s_p   += __shfl_down(s_p,   o, 64);
        s_bce += __shfl_down(s_bce, o, 64);
        c_t    += __shfl_down(c_t,    o, 64);
        c_area += __shfl_down(c_area, o, 64);
        c_inter+= __shfl_down(c_inter,o, 64);
        xmn = min(xmn, __shfl_down(xmn, o, 64));
        ymn = min(ymn, __shfl_down(ymn, o, 64));
        xmx = max(xmx, __shfl_down(xmx, o, 64));
        ymx = max(ymx, __shfl_down(ymx, o, 64));
    }

    // --- cross-wave (4 waves) via LDS ---
    __shared__ float smf[3][4];
    __shared__ int   smi[7][4];
    if (l == 0) {
        smf[0][wv] = s_pt;  smf[1][wv] = s_p;  smf[2][wv] = s_bce;
        smi[0][wv] = c_t;   smi[1][wv] = c_area; smi[2][wv] = c_inter;
        smi[3][wv] = xmn;   smi[4][wv] = ymn;
        smi[5][wv] = xmx;   smi[6][wv] = ymx;
    }
    __syncthreads();
    if (threadIdx.x == 0) {
        float a0 = 0.f, a1 = 0.f, a2 = 0.f;
        int i0 = 0, i1 = 0, i2 = 0;
        int m3 = W, m4 = H, m5 = -1, m6 = -1;
        #pragma unroll
        for (int w = 0; w < 4; ++w) {
            a0 += smf[0][w]; a1 += smf[1][w]; a2 += smf[2][w];
            i0 += smi[0][w]; i1 += smi[1][w]; i2 += smi[2][w];
            m3 = min(m3, smi[3][w]); m4 = min(m4, smi[4][w]);
            m5 = max(m5, smi[5][w]); m6 = max(m6, smi[6][w]);
        }
        const int idx = b * nchunk + chunk;
        wf[0 * N + idx] = a0; wf[1 * N + idx] = a1; wf[2 * N + idx] = a2;
        wi[0 * N + idx] = i0; wi[1 * N + idx] = i1; wi[2 * N + idx] = i2;
        wi[3 * N + idx] = m3; wi[4 * N + idx] = m4;
        wi[5 * N + idx] = m5; wi[6 * N + idx] = m6;
    }
}

// ---------------------------------------------------------------------------
// Kernel 2: 256 threads, 4 per sample; shfl_xor width-4 fold, then per-sample
// box math on lanes with q==0, then block sum.
// ---------------------------------------------------------------------------
__global__ __launch_bounds__(TPB)
void uh_final(const float* __restrict__ pred_bbox,
              const float* __restrict__ gt_bbox,
              const int* __restrict__ pH, const int* __restrict__ pW,
              const float* __restrict__ wf, const int* __restrict__ wi,
              int B, int HW, int nchunk, float* __restrict__ out)
{
    const int W = *pW, H = *pH;
    const int N = B * nchunk;
    const int tid = threadIdx.x;
    const int b   = tid >> 2;          // sample (B=64 assumed <= TPB/4)
    const int q   = tid & 3;           // quarter index

    float v = 0.f;
    if (b < B) {
        float s_pt = 0.f, s_p = 0.f, s_bce = 0.f;
        int c_t = 0, c_area = 0, c_inter = 0;
        int xmn = W, ymn = H, xmx = -1, ymx = -1;
        for (int c = q; c < nchunk; c += 4) {
            const int idx = b * nchunk + c;
            s_pt  += wf[0 * N + idx];
            s_p   += wf[1 * N + idx];
            s_bce += wf[2 * N + idx];
            c_t    += wi[0 * N + idx];
            c_area += wi[1 * N + idx];
            c_inter+= wi[2 * N + idx];
            xmn = min(xmn, wi[3 * N + idx]); ymn = min(ymn, wi[4 * N + idx]);
            xmx = max(xmx, wi[5 * N + idx]); ymx = max(ymx, wi[6 * N + idx]);
        }
        // fold the 4 lanes of this sample
        #pragma unroll
        for (int o = 1; o < 4; o <<= 1) {
            s_pt  += __shfl_xor(s_pt,  o, 64);
            s_p   += __shfl_xor(s_p,   o, 64);
            s_bce += __shfl_xor(s_bce, o, 64);
            c_t    += __shfl_xor(c_t,    o, 64);
            c_area += __shfl_xor(c_area, o, 64);
            c_inter+= __shfl_xor(c_inter,o, 64);
            xmn = min(xmn, __shfl_xor(xmn, o, 64));
            ymn = min(ymn, __shfl_xor(ymn, o, 64));
            xmx = max(xmx, __shfl_xor(xmx, o, 64));
            ymx = max(ymx, __shfl_xor(ymx, o, 64));
        }

        if (q == 0) {
            // ---- dice ----
            float dice = 1.f - (2.f * s_pt + 1.f) / (s_p + (float)c_t + 1.f);

            // ---- det loss ----
            float pb[4] = {pred_bbox[b*4+0], pred_bbox[b*4+1],
                           pred_bbox[b*4+2], pred_bbox[b*4+3]};
            float g0 = gt_bbox[b*4+0], g1 = gt_bbox[b*4+1];
            float g2 = gt_bbox[b*4+2], g3 = gt_bbox[b*4+3];
            float gx1 = g0 * (0.45f * (float)W);
            float gy1 = g1 * (0.45f * (float)H);
            float gx2 = gx1 + 1.0f + g2 * (0.5f * (float)W);
            float gy2 = gy1 + 1.0f + g3 * (0.5f * (float)H);
            float gt[4] = { ((gx1 + gx2) * 0.5f) / (float)H,
                            ((gy1 + gy2) * 0.5f) / (float)W,
                            (gx2 - gx1) / (float)H,
                            (gy2 - gy1) / (float)W };
            float det = 0.025f * box_loss_xywh(pb, gt);

            // ---- s2b ----
            float iou_s2b = (c_area > 0)
                              ? (float)c_inter / fmaxf((float)c_area, 1.f) : 0.f;
            float s2b = 1.f - iou_s2b;

            // ---- b2s ----
            float ox1, oy1, ox2, oy2;
            if (c_area > 0) {
                ox1 = (float)xmn; oy1 = (float)ymn;
                ox2 = (float)xmx; oy2 = (float)ymx;
            } else {
                ox1 = oy1 = ox2 = oy2 = 0.f;
            }
            ox1 /= (float)W; ox2 /= (float)W;
            oy1 /= (float)H; oy2 /= (float)H;
            float ow[4] = { (ox1 + ox2) * 0.5f, (oy1 + oy2) * 0.5f,
                            ox2 - ox1, oy2 - oy1 };
            float px1 = pb[0] - 0.5f * pb[2], py1 = pb[1] - 0.5f * pb[3];
            float px2 = pb[0] + 0.5f * pb[2], py2 = pb[1] + 0.5f * pb[3];
            float pw[4] = { (px1 + px2) * 0.5f, (py1 + py2) * 0.5f,
                            px2 - px1, py2 - py1 };
            float b2s = box_loss_xywh(ow, pw);

            v = dice + s_bce / (float)HW + det + s2b + b2s;
        }
    }

    // block-wide sum of v (non-zero only on q==0 lanes)
    #pragma unroll
    for (int o = 32; o; o >>= 1) v += __shfl_down(v, o, 64);
    __shared__ float sv[4];
    if ((tid & 63) == 0) sv[tid >> 6] = v;
    __syncthreads();
    if (tid == 0) out[0] = (sv[0] + sv[1] + sv[2] + sv[3]) / (float)B;
}

extern "C" void kernel_launch(void* const* d_in, const int* in_sizes, int n_in,
                              void* d_out, int out_size, void* d_ws, size_t ws_size,
                              hipStream_t stream) {
    const float* pred_mask   = (const float*)d_in[0];
    const float* pred_bbox   = (const float*)d_in[1];
    const float* gt_bbox     = (const float*)d_in[2];
    const int*   target_mask = (const int*)d_in[3];
    const int*   pH          = (const int*)d_in[4];
    const int*   pW          = (const int*)d_in[5];
    float* out = (float*)d_out;

    const int B  = in_sizes[1] / 4;       // pred_bbox is (B,4)
    const int HW = in_sizes[0] / B;       // pred_mask is (B,1,H,W)
    const int W  = 512;                    // H*W known; W read on device; for
    const int H  = HW / W;                 // grid sizing assume W=512 layout
    (void)W;

    const int bps = H / 8;                // 8 rows per chunk -> 64 chunks
    const int N   = B * bps;

    float* wf = (float*)d_ws;               // [3][N] float partials
    int*   wi = (int*)d_ws + (size_t)3 * N; // [7][N] int partials

    dim3 grid(bps, B);
    uh_reduce<<<grid, TPB, 0, stream>>>(pred_mask, target_mask, pred_bbox,
                                        pH, pW, wf, wi, HW, N);
    uh_final<<<1, TPB, 0, stream>>>(pred_bbox, gt_bbox, pH, pW, wf, wi,
                                    B, HW, bps, out);
}